// Round 3
// baseline (11281.750 us; speedup 1.0000x reference)
//
#include <hip/hip_runtime.h>

#define H 1024
#define NS 32
#define SS 256
#define T_Q 16384            /* query tokens  (64 x 256) */
#define M_S 8192             /* support tokens (32 x 256) */
#define CH 4096              /* tokens per processing chunk */
#define SENT_PER_CH (CH/SS)  /* 16 sentences per chunk */

// ---------------- sentinel: proves launches + d_out writes work ----------------
__global__ void sentinel_kernel(float* __restrict__ out, int n)
{
  int i = blockIdx.x * 256 + threadIdx.x;
  if (i < n) out[i] = 1000.0f;
}

// ---------------- GEMM: C = act( [acc?C:0] + A@W + bias ), all fp32 ----------------
// A: [M,K], W: [K,N] row-major, C: [M,N]. 64x64 tile, 256 thr, 4x4 micro, BK=16.
__global__ __launch_bounds__(256) void gemm_f32(
    const float* __restrict__ A, const float* __restrict__ W,
    const float* __restrict__ bias, float* __restrict__ C,
    int M, int N, int K, int relu, int accflag)
{
  const int BM = 64, BN = 64, BK = 16;
  __shared__ float As[BK][BM];
  __shared__ float Bs[BK][BN];
  int tid = threadIdx.x;
  int tx = tid & 15, ty = tid >> 4;
  int bn0 = blockIdx.x * BN;
  int bm0 = blockIdx.y * BM;

  float acc[4][4] = {};

  int am = tid >> 2;          // 0..63
  int ak = (tid & 3) * 4;     // 0,4,8,12
  int bk = tid >> 4;          // 0..15
  int bn = (tid & 15) * 4;

  const float* Aptr = A + (size_t)(bm0 + am) * K + ak;
  const float* Wptr = W + (size_t)bk * N + bn0 + bn;

  for (int k0 = 0; k0 < K; k0 += BK) {
#pragma unroll
    for (int c = 0; c < 4; c++) As[ak + c][am] = Aptr[c];
#pragma unroll
    for (int c = 0; c < 4; c++) Bs[bk][bn + c] = Wptr[c];
    __syncthreads();
#pragma unroll
    for (int k = 0; k < BK; k++) {
      float a[4], b[4];
#pragma unroll
      for (int i = 0; i < 4; i++) a[i] = As[k][ty * 4 + i];
#pragma unroll
      for (int j = 0; j < 4; j++) b[j] = Bs[k][tx * 4 + j];
#pragma unroll
      for (int i = 0; i < 4; i++)
#pragma unroll
        for (int j = 0; j < 4; j++)
          acc[i][j] += a[i] * b[j];
    }
    __syncthreads();
    Aptr += BK;
    Wptr += (size_t)BK * N;
  }

#pragma unroll
  for (int i = 0; i < 4; i++) {
    int m = bm0 + ty * 4 + i;
    float* Crow = C + (size_t)m * N + bn0;
#pragma unroll
    for (int j = 0; j < 4; j++) {
      int n = tx * 4 + j;
      float v = acc[i][j];
      if (bias)    v += bias[bn0 + n];
      if (accflag) v += Crow[n];
      if (relu)    v = fmaxf(v, 0.0f);
      Crow[n] = v;
    }
  }
}

// ---------------- LayerNorm over last dim (H=1024), in place ----------------
__global__ __launch_bounds__(256) void ln_kernel(
    float* __restrict__ h, const float* __restrict__ g, const float* __restrict__ be)
{
  int row = blockIdx.x;
  float* p = h + (size_t)row * H;
  int tid = threadIdx.x;
  float v[4];
  float s = 0.f, sq = 0.f;
#pragma unroll
  for (int j = 0; j < 4; j++) { v[j] = p[tid + 256 * j]; s += v[j]; sq += v[j] * v[j]; }
  __shared__ float rs[256], rq[256];
  rs[tid] = s; rq[tid] = sq; __syncthreads();
  for (int o = 128; o; o >>= 1) {
    if (tid < o) { rs[tid] += rs[tid + o]; rq[tid] += rq[tid + o]; }
    __syncthreads();
  }
  float mu   = rs[0] * (1.0f / H);
  float var  = rq[0] * (1.0f / H) - mu * mu;
  float rstd = rsqrtf(var + 1e-5f);
#pragma unroll
  for (int j = 0; j < 4; j++) {
    int hi = tid + 256 * j;
    p[hi] = g[hi] * (v[j] - mu) * rstd + be[hi];
  }
}

// ------------- per-sentence masked-mean prototypes (one block per sentence) -------------
// enc: encoded chunk [SENT_PER_CH*SS, H]; labels: this chunk's labels; protos_out: [SENT_PER_CH, H]
__global__ __launch_bounds__(256) void proto_kernel(
    const float* __restrict__ enc, const int* __restrict__ labels,
    float* __restrict__ protos_out)
{
  int p = blockIdx.x;          // sentence within chunk
  int tid = threadIdx.x;
  __shared__ unsigned char lbl[SS];
  lbl[tid] = (labels[p * SS + tid] > 0) ? 1 : 0;
  __syncthreads();
  float acc[4] = {0.f, 0.f, 0.f, 0.f};
  int cnt = 0;
  const float* base = enc + (size_t)p * SS * H;
  for (int s = 0; s < SS; s++) {
    if (lbl[s]) {
      cnt++;
      const float* r = base + (size_t)s * H;
#pragma unroll
      for (int j = 0; j < 4; j++) acc[j] += r[tid + 256 * j];
    }
  }
  float ic = 1.0f / fmaxf((float)cnt, 1.0f);
#pragma unroll
  for (int j = 0; j < 4; j++) protos_out[p * H + tid + 256 * j] = acc[j] * ic;
}

// ---------------- normalize prototypes -> pn ----------------
__global__ __launch_bounds__(256) void pn_kernel(
    const float* __restrict__ protos, float* __restrict__ pn)
{
  int p = blockIdx.x;
  int tid = threadIdx.x;
  __shared__ float red[256];
  float v[4];
  float sq = 0.f;
#pragma unroll
  for (int j = 0; j < 4; j++) { v[j] = protos[p * H + tid + 256 * j]; sq += v[j] * v[j]; }
  red[tid] = sq; __syncthreads();
  for (int o = 128; o; o >>= 1) {
    if (tid < o) red[tid] += red[tid + o];
    __syncthreads();
  }
  float inv = 1.0f / fmaxf(sqrtf(red[0]), 1e-8f);
#pragma unroll
  for (int j = 0; j < 4; j++) pn[p * H + tid + 256 * j] = v[j] * inv;
}

// ---- fused cosine-sims + softmax + influence: xout[t] = src[t] + softmax(cos(src,pn))@protos ----
__device__ __forceinline__ float wred(float v) {
#pragma unroll
  for (int o = 32; o; o >>= 1) v += __shfl_xor(v, o, 64);
  return v;
}

__global__ __launch_bounds__(64) void adapt_kernel(
    const float* __restrict__ src, const float* __restrict__ protos,
    const float* __restrict__ pn, float* __restrict__ xout)
{
  int t = blockIdx.x;
  int lane = threadIdx.x;
  const float* ar = src + (size_t)t * H;
  float a[16];
  float ss = 0.f;
#pragma unroll
  for (int j = 0; j < 16; j++) { a[j] = ar[j * 64 + lane]; ss += a[j] * a[j]; }
  ss = wred(ss);
  float inv = 1.0f / fmaxf(sqrtf(ss), 1e-8f);
  float sims[NS];
#pragma unroll
  for (int p = 0; p < NS; p++) {
    const float* pr = pn + p * H;
    float part = 0.f;
#pragma unroll
    for (int j = 0; j < 16; j++) part += a[j] * pr[j * 64 + lane];
    sims[p] = wred(part) * inv;
  }
  float mx = -1e30f;
#pragma unroll
  for (int p = 0; p < NS; p++) mx = fmaxf(mx, sims[p]);
  float sum = 0.f;
#pragma unroll
  for (int p = 0; p < NS; p++) { float e = __expf(sims[p] - mx); sims[p] = e; sum += e; }
  float is = 1.0f / sum;
  float* xr = xout + (size_t)t * H;
#pragma unroll
  for (int j = 0; j < 16; j++) {
    float v = a[j];
#pragma unroll
    for (int p = 0; p < NS; p++) v += sims[p] * is * protos[p * H + j * 64 + lane];
    xr[j * 64 + lane] = v;
  }
}

// ---------------- preds chunk: out[t0+t, c] = h2[t]@W3[:,c] + b3[c] ----------------
__global__ __launch_bounds__(256) void FewShotABSALearner_46935402610855_kernel(
    const float* __restrict__ h2, const float* __restrict__ W3,
    const float* __restrict__ b3, float* __restrict__ out,
    int t0, int out_size)
{
  int idx = blockIdx.x * 256 + threadIdx.x;
  if (idx >= CH * 3) return;
  int t = idx / 3, c = idx - t * 3;
  float acc = b3[c];
  const float* hr = h2 + (size_t)t * 64;
#pragma unroll
  for (int k = 0; k < 64; k++) acc += hr[k] * W3[k * 3 + c];
  int oi = t0 * 3 + idx;
  if (oi < out_size) out[oi] = acc;
}

extern "C" void kernel_launch(void* const* d_in, const int* in_sizes, int n_in,
                              void* d_out, int out_size, void* d_ws, size_t ws_size,
                              hipStream_t stream)
{
  (void)in_sizes; (void)n_in; (void)ws_size;
  const float* sup   = (const float*)d_in[0];
  const float* qry   = (const float*)d_in[1];
  const int*   lab   = (const int*)d_in[2];
  const float *aw_W1 = (const float*)d_in[3],  *aw_b1 = (const float*)d_in[4];
  const float *aw_W2 = (const float*)d_in[5],  *aw_b2 = (const float*)d_in[6];
  const float *aw_g  = (const float*)d_in[7],  *aw_be = (const float*)d_in[8];
  const float *ct_W1 = (const float*)d_in[9],  *ct_b1 = (const float*)d_in[10];
  const float *ct_W2 = (const float*)d_in[11], *ct_b2 = (const float*)d_in[12];
  const float *ct_g  = (const float*)d_in[13], *ct_be = (const float*)d_in[14];
  const float *ad_W1 = (const float*)d_in[15], *ad_b1 = (const float*)d_in[16];
  const float *ad_W2 = (const float*)d_in[17], *ad_b2 = (const float*)d_in[18];
  const float *cl_W1 = (const float*)d_in[19], *cl_b1 = (const float*)d_in[20];
  const float *cl_W2 = (const float*)d_in[21], *cl_b2 = (const float*)d_in[22];
  const float *cl_W3 = (const float*)d_in[23], *cl_b3 = (const float*)d_in[24];
  float* out = (float*)d_out;

  // workspace layout (~50 MB total)
  char* ws = (char*)d_ws;
  float* A      = (float*)(ws);                        // 16 MB [CH x H]
  float* B      = (float*)(ws + ((size_t)16 << 20));   // 16 MB
  float* Cb     = (float*)(ws + ((size_t)32 << 20));   // 16 MB
  float* protos = (float*)(ws + ((size_t)48 << 20));   // 128 KB [NS x H]
  float* pn     = protos + NS * H;                     // 128 KB
  float* h2c    = pn + NS * H;                         // 1 MB  [CH x 64]

  dim3 blk(256);
  dim3 gg(H / 64, CH / 64);       // [16, 64] chunk GEMM grid

  // 0) sentinel — if the pipeline below executes, it overwrites this
  sentinel_kernel<<<(out_size + 255) / 256, blk, 0, stream>>>(out, out_size);

  // 1) support chunks -> prototypes
  for (int sc = 0; sc < M_S / CH; sc++) {
    const float* s0 = sup + (size_t)sc * CH * H;
    gemm_f32<<<gg, blk, 0, stream>>>(s0, aw_W1, aw_b1, B,  CH, H, H, 1, 0);
    gemm_f32<<<gg, blk, 0, stream>>>(B,  aw_W2, aw_b2, Cb, CH, H, H, 0, 0);
    ln_kernel<<<CH, blk, 0, stream>>>(Cb, aw_g, aw_be);
    proto_kernel<<<SENT_PER_CH, blk, 0, stream>>>(Cb, lab + sc * CH,
                                                  protos + (size_t)sc * SENT_PER_CH * H);
  }
  pn_kernel<<<NS, blk, 0, stream>>>(protos, pn);

  // 2) query chunks: 5 adaptation steps + heads + classifier
  for (int qc = 0; qc < T_Q / CH; qc++) {
    const float* q0 = qry + (size_t)qc * CH * H;
    // iter 0 reads the query embeddings directly
    adapt_kernel<<<CH, 64, 0, stream>>>(q0, protos, pn, B);
    gemm_f32<<<gg, blk, 0, stream>>>(B,  ad_W1, ad_b1, Cb, CH, H, H, 1, 0);
    gemm_f32<<<gg, blk, 0, stream>>>(Cb, ad_W2, ad_b2, A,  CH, H, H, 0, 0);
    for (int it = 1; it < 5; it++) {
      adapt_kernel<<<CH, 64, 0, stream>>>(A, protos, pn, B);
      gemm_f32<<<gg, blk, 0, stream>>>(B,  ad_W1, ad_b1, Cb, CH, H, H, 1, 0);
      gemm_f32<<<gg, blk, 0, stream>>>(Cb, ad_W2, ad_b2, A,  CH, H, H, 0, 0);
    }
    // aspect_aware head: Cb = ln(relu(A@aw_W1+b1)@aw_W2+b2)
    gemm_f32<<<gg, blk, 0, stream>>>(A, aw_W1, aw_b1, B,  CH, H, H, 1, 0);
    gemm_f32<<<gg, blk, 0, stream>>>(B, aw_W2, aw_b2, Cb, CH, H, H, 0, 0);
    ln_kernel<<<CH, blk, 0, stream>>>(Cb, aw_g, aw_be);          // Cb = q_aw
    // contrastive head: A = ln(relu(A@ct_W1+b1)@ct_W2+b2)  (A consumed, then reused)
    gemm_f32<<<gg, blk, 0, stream>>>(A, ct_W1, ct_b1, B, CH, H, H, 1, 0);
    gemm_f32<<<gg, blk, 0, stream>>>(B, ct_W2, ct_b2, A, CH, H, H, 0, 0);
    ln_kernel<<<CH, blk, 0, stream>>>(A, ct_g, ct_be);           // A = q_ct
    // classifier: B = relu(q_aw@W1[0:H] + q_ct@W1[H:2H] + b1)
    gemm_f32<<<gg, blk, 0, stream>>>(Cb, cl_W1,                 nullptr, B, CH, H, H, 0, 0);
    gemm_f32<<<gg, blk, 0, stream>>>(A,  cl_W1 + (size_t)H * H, cl_b1,   B, CH, H, H, 1, 1);
    // h2 = relu(B@cl_W2+b2)  [CH x 64]
    gemm_f32<<<dim3(1, CH / 64), blk, 0, stream>>>(B, cl_W2, cl_b2, h2c, CH, 64, H, 1, 0);
    // preds -> d_out
    FewShotABSALearner_46935402610855_kernel<<<(CH * 3 + 255) / 256, blk, 0, stream>>>(
        h2c, cl_W3, cl_b3, out, qc * CH, out_size);
  }
}

// Round 5
// 7462.360 us; speedup vs baseline: 1.5118x; 1.5118x over previous
//
#include <hip/hip_runtime.h>
#include <hip/hip_bf16.h>

#define H 1024
#define NS 32
#define SS 256
#define T_Q 16384            /* query tokens  (64 x 256) */
#define M_S 8192             /* support tokens (32 x 256) */

typedef __hip_bfloat16 bf16;
typedef short short8 __attribute__((ext_vector_type(8)));
typedef float floatx4 __attribute__((ext_vector_type(4)));

__device__ __forceinline__ float ldf(const bf16& v) { return __bfloat162float(v); }

// two-term bf16 split: v ~= hi + lo  (residual ~2^-16 relative)
__device__ __forceinline__ void split2(float v, bf16& h, bf16& l) {
  h = __float2bfloat16(v);
  l = __float2bfloat16(v - __bfloat162float(h));
}

// async global->LDS, 16B per lane; LDS dest = wave-uniform base + lane*16
__device__ __forceinline__ void gl2lds16(const void* g, void* l) {
  __builtin_amdgcn_global_load_lds(
      (const __attribute__((address_space(1))) unsigned int*)g,
      (__attribute__((address_space(3))) unsigned int*)l, 16, 0, 0);
}

// ---------------- fp32 -> bf16 hi/lo split convert ----------------
__global__ __launch_bounds__(256) void conv_split(const float* __restrict__ in,
                                                  bf16* __restrict__ oh,
                                                  bf16* __restrict__ ol, int n)
{
  int i = blockIdx.x * 256 + threadIdx.x;
  if (i < n) { bf16 h, l; split2(in[i], h, l); oh[i] = h; ol[i] = l; }
}

// -------- transpose + split: Wh/Wl[n][k] = split(W[k][n]).  grid (N/32, K/32) --------
__global__ __launch_bounds__(256) void transpose_split(
    const float* __restrict__ W, bf16* __restrict__ Wh, bf16* __restrict__ Wl,
    int K, int N)
{
  __shared__ float t[32][33];
  int n0 = blockIdx.x * 32, k0 = blockIdx.y * 32;
  int tx = threadIdx.x & 31, ty = threadIdx.x >> 5;
#pragma unroll
  for (int i = 0; i < 32; i += 8)
    t[ty + i][tx] = W[(size_t)(k0 + ty + i) * N + (n0 + tx)];
  __syncthreads();
#pragma unroll
  for (int i = 0; i < 32; i += 8) {
    bf16 h, l; split2(t[tx][ty + i], h, l);
    size_t o = (size_t)(n0 + ty + i) * K + (k0 + tx);
    Wh[o] = h;
    if (Wl) Wl[o] = l;
  }
}

// ---------------- split-bf16 MFMA GEMM ----------------
// C = act( [A0|A1] @ Wt^T + bias ),  computed as Ah@Wh + Al@Wh + Ah@Wl.
// A rows have stride H (=1024). Wt: [N, Ktot] pre-transposed. C: hi/lo bf16 pair [M,N].
// 128x128 tile, 256 thr (4 waves 2x2), 16x16x32 MFMA, BK=32.
template<bool RELU>
__global__ __launch_bounds__(256) void gemm3(
    const bf16* __restrict__ A0h, const bf16* __restrict__ A0l,
    const bf16* __restrict__ A1h, const bf16* __restrict__ A1l,
    const bf16* __restrict__ Wh,  const bf16* __restrict__ Wl,
    const float* __restrict__ bias,
    bf16* __restrict__ Ch, bf16* __restrict__ Cl,
    int M, int N, int K0, int Ktot)
{
  __shared__ bf16 Ash[128 * 32];
  __shared__ bf16 Asl[128 * 32];
  __shared__ bf16 Bsh[128 * 32];
  __shared__ bf16 Bsl[128 * 32];
  const int tid = threadIdx.x;
  const int w = tid >> 6, l = tid & 63;
  const int bm0 = blockIdx.y * 128, bn0 = blockIdx.x * 128;
  const int wr = (w >> 1) * 64, wc = (w & 1) * 64;
  const int m16 = l & 15, quad = l >> 4;
  const bool haveWl = (Wl != nullptr);

  floatx4 acc[4][4];
#pragma unroll
  for (int i = 0; i < 4; i++)
#pragma unroll
    for (int j = 0; j < 4; j++) { acc[i][j][0]=0.f; acc[i][j][1]=0.f; acc[i][j][2]=0.f; acc[i][j][3]=0.f; }

  const int ar = w * 16 + (l >> 2);   // staging row (0..63) within half-tile
  const int ac = (l & 3) * 8;         // staging k-offset (elements)

  for (int k0 = 0; k0 < Ktot; k0 += 32) {
    const bf16 *Abh, *Abl;
    if (k0 < K0) { Abh = A0h + k0; Abl = A0l + k0; }
    else         { Abh = A1h + (k0 - K0); Abl = A1l + (k0 - K0); }
    gl2lds16(Abh + (size_t)(bm0 + ar) * H + ac,      &Ash[w * 512]);
    gl2lds16(Abh + (size_t)(bm0 + 64 + ar) * H + ac, &Ash[2048 + w * 512]);
    gl2lds16(Abl + (size_t)(bm0 + ar) * H + ac,      &Asl[w * 512]);
    gl2lds16(Abl + (size_t)(bm0 + 64 + ar) * H + ac, &Asl[2048 + w * 512]);
    const bf16* Bbh = Wh + k0;
    gl2lds16(Bbh + (size_t)(bn0 + ar) * Ktot + ac,      &Bsh[w * 512]);
    gl2lds16(Bbh + (size_t)(bn0 + 64 + ar) * Ktot + ac, &Bsh[2048 + w * 512]);
    if (haveWl) {
      const bf16* Bbl = Wl + k0;
      gl2lds16(Bbl + (size_t)(bn0 + ar) * Ktot + ac,      &Bsl[w * 512]);
      gl2lds16(Bbl + (size_t)(bn0 + 64 + ar) * Ktot + ac, &Bsl[2048 + w * 512]);
    }
    __syncthreads();

    short8 afh[4], afl[4], bfh[4], bfl[4];
#pragma unroll
    for (int mt = 0; mt < 4; mt++) {
      afh[mt] = *(const short8*)&Ash[(wr + mt * 16 + m16) * 32 + quad * 8];
      afl[mt] = *(const short8*)&Asl[(wr + mt * 16 + m16) * 32 + quad * 8];
    }
#pragma unroll
    for (int nt = 0; nt < 4; nt++)
      bfh[nt] = *(const short8*)&Bsh[(wc + nt * 16 + m16) * 32 + quad * 8];
    if (haveWl) {
#pragma unroll
      for (int nt = 0; nt < 4; nt++)
        bfl[nt] = *(const short8*)&Bsl[(wc + nt * 16 + m16) * 32 + quad * 8];
    }
#pragma unroll
    for (int mt = 0; mt < 4; mt++)
#pragma unroll
      for (int nt = 0; nt < 4; nt++) {
        acc[mt][nt] = __builtin_amdgcn_mfma_f32_16x16x32_bf16(afh[mt], bfh[nt], acc[mt][nt], 0, 0, 0);
        acc[mt][nt] = __builtin_amdgcn_mfma_f32_16x16x32_bf16(afl[mt], bfh[nt], acc[mt][nt], 0, 0, 0);
      }
    if (haveWl) {
#pragma unroll
      for (int mt = 0; mt < 4; mt++)
#pragma unroll
        for (int nt = 0; nt < 4; nt++)
          acc[mt][nt] = __builtin_amdgcn_mfma_f32_16x16x32_bf16(afh[mt], bfl[nt], acc[mt][nt], 0, 0, 0);
    }
    __syncthreads();
  }

  // epilogue: C/D layout col=lane&15, row=quad*4+reg
#pragma unroll
  for (int mt = 0; mt < 4; mt++) {
#pragma unroll
    for (int nt = 0; nt < 4; nt++) {
      int row0 = bm0 + wr + mt * 16 + quad * 4;
      int col  = bn0 + wc + nt * 16 + m16;
      float bv = bias ? bias[col] : 0.f;
#pragma unroll
      for (int r = 0; r < 4; r++) {
        float v = acc[mt][nt][r] + bv;
        if (RELU) v = fmaxf(v, 0.f);
        bf16 h, lo; split2(v, h, lo);
        size_t o = (size_t)(row0 + r) * N + col;
        Ch[o] = h; Cl[o] = lo;
      }
    }
  }
}

// ---------------- LayerNorm on hi/lo pair (fp32 stats), in place ----------------
__global__ __launch_bounds__(256) void ln_pair(
    bf16* __restrict__ hh, bf16* __restrict__ hl,
    const float* __restrict__ g, const float* __restrict__ be)
{
  int row = blockIdx.x;
  bf16* ph = hh + (size_t)row * H;
  bf16* pl = hl + (size_t)row * H;
  int tid = threadIdx.x;
  float v[4];
  float s = 0.f, sq = 0.f;
#pragma unroll
  for (int j = 0; j < 4; j++) {
    int hi = tid + 256 * j;
    v[j] = ldf(ph[hi]) + ldf(pl[hi]);
    s += v[j]; sq += v[j] * v[j];
  }
  __shared__ float rs[256], rq[256];
  rs[tid] = s; rq[tid] = sq; __syncthreads();
  for (int o = 128; o; o >>= 1) {
    if (tid < o) { rs[tid] += rs[tid + o]; rq[tid] += rq[tid + o]; }
    __syncthreads();
  }
  float mu   = rs[0] * (1.0f / H);
  float var  = rq[0] * (1.0f / H) - mu * mu;
  float rstd = rsqrtf(var + 1e-5f);
#pragma unroll
  for (int j = 0; j < 4; j++) {
    int hi = tid + 256 * j;
    bf16 h, l; split2(g[hi] * (v[j] - mu) * rstd + be[hi], h, l);
    ph[hi] = h; pl[hi] = l;
  }
}

// ------------- per-sentence masked-mean prototypes (pair in, fp32 out) -------------
__global__ __launch_bounds__(256) void proto_kernel(
    const bf16* __restrict__ eh, const bf16* __restrict__ el,
    const int* __restrict__ labels, float* __restrict__ protos_out)
{
  int p = blockIdx.x;
  int tid = threadIdx.x;
  __shared__ unsigned char lbl[SS];
  lbl[tid] = (labels[p * SS + tid] > 0) ? 1 : 0;
  __syncthreads();
  float acc[4] = {0.f, 0.f, 0.f, 0.f};
  int cnt = 0;
  const bf16* bh = eh + (size_t)p * SS * H;
  const bf16* bl = el + (size_t)p * SS * H;
  for (int s = 0; s < SS; s++) {
    if (lbl[s]) {
      cnt++;
      const bf16* rh = bh + (size_t)s * H;
      const bf16* rl = bl + (size_t)s * H;
#pragma unroll
      for (int j = 0; j < 4; j++)
        acc[j] += ldf(rh[tid + 256 * j]) + ldf(rl[tid + 256 * j]);
    }
  }
  float ic = 1.0f / fmaxf((float)cnt, 1.0f);
#pragma unroll
  for (int j = 0; j < 4; j++) protos_out[p * H + tid + 256 * j] = acc[j] * ic;
}

// ---------------- normalize prototypes -> pn (fp32) ----------------
__global__ __launch_bounds__(256) void pn_kernel(
    const float* __restrict__ protos, float* __restrict__ pn)
{
  int p = blockIdx.x;
  int tid = threadIdx.x;
  __shared__ float red[256];
  float v[4];
  float sq = 0.f;
#pragma unroll
  for (int j = 0; j < 4; j++) { v[j] = protos[p * H + tid + 256 * j]; sq += v[j] * v[j]; }
  red[tid] = sq; __syncthreads();
  for (int o = 128; o; o >>= 1) {
    if (tid < o) red[tid] += red[tid + o];
    __syncthreads();
  }
  float inv = 1.0f / fmaxf(sqrtf(red[0]), 1e-8f);
#pragma unroll
  for (int j = 0; j < 4; j++) pn[p * H + tid + 256 * j] = v[j] * inv;
}

// ---- fused cosine-sims + softmax + influence; writes hi/lo pair ----
__device__ __forceinline__ float wred(float v) {
#pragma unroll
  for (int o = 32; o; o >>= 1) v += __shfl_xor(v, o, 64);
  return v;
}

__device__ __forceinline__ void adapt_body(
    const float a_in[16], const float* __restrict__ protos,
    const float* __restrict__ pn, bf16* __restrict__ xh, bf16* __restrict__ xl,
    int t, int lane)
{
  float a[16];
  float ss = 0.f;
#pragma unroll
  for (int j = 0; j < 16; j++) { a[j] = a_in[j]; ss += a[j] * a[j]; }
  ss = wred(ss);
  float inv = 1.0f / fmaxf(sqrtf(ss), 1e-8f);
  float sims[NS];
#pragma unroll
  for (int p = 0; p < NS; p++) {
    const float* pr = pn + p * H;
    float part = 0.f;
#pragma unroll
    for (int j = 0; j < 16; j++) part += a[j] * pr[j * 64 + lane];
    sims[p] = wred(part) * inv;
  }
  float mx = -1e30f;
#pragma unroll
  for (int p = 0; p < NS; p++) mx = fmaxf(mx, sims[p]);
  float sum = 0.f;
#pragma unroll
  for (int p = 0; p < NS; p++) { float e = __expf(sims[p] - mx); sims[p] = e; sum += e; }
  float is = 1.0f / sum;
  bf16* xrh = xh + (size_t)t * H;
  bf16* xrl = xl + (size_t)t * H;
#pragma unroll
  for (int j = 0; j < 16; j++) {
    float v = a[j];
#pragma unroll
    for (int p = 0; p < NS; p++) v += sims[p] * is * protos[p * H + j * 64 + lane];
    bf16 h, l; split2(v, h, l);
    xrh[j * 64 + lane] = h; xrl[j * 64 + lane] = l;
  }
}

__global__ __launch_bounds__(64) void adapt_f(
    const float* __restrict__ src, const float* __restrict__ protos,
    const float* __restrict__ pn, bf16* __restrict__ xh, bf16* __restrict__ xl)
{
  int t = blockIdx.x, lane = threadIdx.x;
  const float* ar = src + (size_t)t * H;
  float a[16];
#pragma unroll
  for (int j = 0; j < 16; j++) a[j] = ar[j * 64 + lane];
  adapt_body(a, protos, pn, xh, xl, t, lane);
}

__global__ __launch_bounds__(64) void adapt_b(
    const bf16* __restrict__ sh, const bf16* __restrict__ sl,
    const float* __restrict__ protos, const float* __restrict__ pn,
    bf16* __restrict__ xh, bf16* __restrict__ xl)
{
  int t = blockIdx.x, lane = threadIdx.x;
  const bf16* arh = sh + (size_t)t * H;
  const bf16* arl = sl + (size_t)t * H;
  float a[16];
#pragma unroll
  for (int j = 0; j < 16; j++) a[j] = ldf(arh[j * 64 + lane]) + ldf(arl[j * 64 + lane]);
  adapt_body(a, protos, pn, xh, xl, t, lane);
}

// -------- small-N GEMM (N=64): h2 = relu(A@W + b); A = bf16 pair, W fp32, out fp32 --------
__global__ __launch_bounds__(256) void gemm_small(
    const bf16* __restrict__ Ah, const bf16* __restrict__ Al,
    const float* __restrict__ W, const float* __restrict__ bias,
    float* __restrict__ C, int M, int N, int K)
{
  const int BK = 16;
  __shared__ float As[BK][64];
  __shared__ float Bs[BK][64];
  int tid = threadIdx.x;
  int tx = tid & 15, ty = tid >> 4;
  int bn0 = blockIdx.x * 64;
  int bm0 = blockIdx.y * 64;
  float acc[4][4] = {};
  int am = tid >> 2, ak = (tid & 3) * 4;
  int bk = tid >> 4, bn = (tid & 15) * 4;
  const bf16* Aph = Ah + (size_t)(bm0 + am) * K + ak;
  const bf16* Apl = Al + (size_t)(bm0 + am) * K + ak;
  const float* Wptr = W + (size_t)bk * N + bn0 + bn;
  for (int k0 = 0; k0 < K; k0 += BK) {
#pragma unroll
    for (int c = 0; c < 4; c++) As[ak + c][am] = ldf(Aph[c]) + ldf(Apl[c]);
#pragma unroll
    for (int c = 0; c < 4; c++) Bs[bk][bn + c] = Wptr[c];
    __syncthreads();
#pragma unroll
    for (int k = 0; k < BK; k++) {
      float a[4], b[4];
#pragma unroll
      for (int i = 0; i < 4; i++) a[i] = As[k][ty * 4 + i];
#pragma unroll
      for (int j = 0; j < 4; j++) b[j] = Bs[k][tx * 4 + j];
#pragma unroll
      for (int i = 0; i < 4; i++)
#pragma unroll
        for (int j = 0; j < 4; j++)
          acc[i][j] += a[i] * b[j];
    }
    __syncthreads();
    Aph += BK; Apl += BK;
    Wptr += (size_t)BK * N;
  }
#pragma unroll
  for (int i = 0; i < 4; i++) {
    float* Crow = C + (size_t)(bm0 + ty * 4 + i) * N + bn0;
#pragma unroll
    for (int j = 0; j < 4; j++) {
      int n = tx * 4 + j;
      Crow[n] = fmaxf(acc[i][j] + bias[bn0 + n], 0.f);
    }
  }
}

// ---------------- preds chunk: out[t0+t, c] = h2[t]@W3[:,c] + b3[c] (fp32) ----------------
__global__ __launch_bounds__(256) void FewShotABSALearner_46935402610855_kernel(
    const float* __restrict__ h2, const float* __restrict__ W3,
    const float* __restrict__ b3, float* __restrict__ out,
    int t0, int nElem, int out_size)
{
  int idx = blockIdx.x * 256 + threadIdx.x;
  if (idx >= nElem) return;
  int t = idx / 3, c = idx - t * 3;
  float acc = b3[c];
  const float* hr = h2 + (size_t)t * 64;
#pragma unroll
  for (int k = 0; k < 64; k++) acc += hr[k] * W3[k * 3 + c];
  int oi = t0 * 3 + idx;
  if (oi < out_size) out[oi] = acc;
}

extern "C" void kernel_launch(void* const* d_in, const int* in_sizes, int n_in,
                              void* d_out, int out_size, void* d_ws, size_t ws_size,
                              hipStream_t stream)
{
  (void)in_sizes; (void)n_in;
  const float* sup   = (const float*)d_in[0];
  const float* qry   = (const float*)d_in[1];
  const int*   lab   = (const int*)d_in[2];
  const float *aw_W1 = (const float*)d_in[3],  *aw_b1 = (const float*)d_in[4];
  const float *aw_W2 = (const float*)d_in[5],  *aw_b2 = (const float*)d_in[6];
  const float *aw_g  = (const float*)d_in[7],  *aw_be = (const float*)d_in[8];
  const float *ct_W1 = (const float*)d_in[9],  *ct_b1 = (const float*)d_in[10];
  const float *ct_W2 = (const float*)d_in[11], *ct_b2 = (const float*)d_in[12];
  const float *ct_g  = (const float*)d_in[13], *ct_be = (const float*)d_in[14];
  const float *ad_W1 = (const float*)d_in[15], *ad_b1 = (const float*)d_in[16];
  const float *ad_W2 = (const float*)d_in[17], *ad_b2 = (const float*)d_in[18];
  const float *cl_W1 = (const float*)d_in[19], *cl_b1 = (const float*)d_in[20];
  const float *cl_W2 = (const float*)d_in[21], *cl_b2 = (const float*)d_in[22];
  const float *cl_W3 = (const float*)d_in[23], *cl_b3 = (const float*)d_in[24];
  float* out = (float*)d_out;

  // ---- adaptive chunk size from ws_size (bytes needed, computed exactly) ----
  // fixed: 12 sq-wt bufs (2MB) + clW1 hi (4MB) [+ clW1 lo 4MB] + protos/pn (256KB)
  // per-C: 6 act bufs (C*1024*2 B each) + h2c (C*256 B)
  const size_t MB = 1 << 20;
  int C; bool clLo = true;
  if      (ws_size >= (size_t)(85200000)) C = 4096;          // 81.3 MB needed
  else if (ws_size >= (size_t)(59510000)) C = 2048;          // 56.8 MB needed
  else if (ws_size >= (size_t)(46670000)) C = 1024;          // 44.5 MB needed
  else { C = 1024; clLo = false; }                           // 40.5 MB needed
  const size_t actB = (size_t)C * H * sizeof(bf16);

  char* ws = (char*)d_ws;
  size_t off = 0;
  auto nxt = [&](size_t b) { char* p = ws + off; off += b; return p; };
  bf16* sqw[12];
  for (int i = 0; i < 12; i++) sqw[i] = (bf16*)nxt(2 * MB);
  bf16 *aw1h = sqw[0], *aw1l = sqw[1], *aw2h = sqw[2],  *aw2l = sqw[3];
  bf16 *ct1h = sqw[4], *ct1l = sqw[5], *ct2h = sqw[6],  *ct2l = sqw[7];
  bf16 *ad1h = sqw[8], *ad1l = sqw[9], *ad2h = sqw[10], *ad2l = sqw[11];
  bf16* clW1h = (bf16*)nxt(4 * MB);
  bf16* clW1l = clLo ? (bf16*)nxt(4 * MB) : nullptr;
  float* protos = (float*)nxt(NS * H * 4);
  float* pn     = (float*)nxt(NS * H * 4);
  float* h2c    = (float*)nxt((size_t)C * 64 * 4);
  bf16 *R0h = (bf16*)nxt(actB), *R0l = (bf16*)nxt(actB);
  bf16 *R1h = (bf16*)nxt(actB), *R1l = (bf16*)nxt(actB);
  bf16 *R2h = (bf16*)nxt(actB), *R2l = (bf16*)nxt(actB);

  dim3 blk(256);
  dim3 tg(32, 32);
  dim3 gg(H / 128, C / 128);

  // ---- weight prep: transpose + hi/lo split ----
  transpose_split<<<tg, blk, 0, stream>>>(aw_W1, aw1h, aw1l, H, H);
  transpose_split<<<tg, blk, 0, stream>>>(aw_W2, aw2h, aw2l, H, H);
  transpose_split<<<tg, blk, 0, stream>>>(ct_W1, ct1h, ct1l, H, H);
  transpose_split<<<tg, blk, 0, stream>>>(ct_W2, ct2h, ct2l, H, H);
  transpose_split<<<tg, blk, 0, stream>>>(ad_W1, ad1h, ad1l, H, H);
  transpose_split<<<tg, blk, 0, stream>>>(ad_W2, ad2h, ad2l, H, H);
  transpose_split<<<dim3(32, 64), blk, 0, stream>>>(cl_W1, clW1h, clW1l, 2 * H, H);

  // ---- support chunks -> prototypes ----
  for (int sc = 0; sc < M_S / C; sc++) {
    conv_split<<<(C * H) / 256, blk, 0, stream>>>(sup + (size_t)sc * C * H, R0h, R0l, C * H);
    gemm3<true ><<<gg, blk, 0, stream>>>(R0h, R0l, R0h, R0l, aw1h, aw1l, aw_b1, R1h, R1l, C, H, H, H);
    gemm3<false><<<gg, blk, 0, stream>>>(R1h, R1l, R1h, R1l, aw2h, aw2l, aw_b2, R2h, R2l, C, H, H, H);
    ln_pair<<<C, blk, 0, stream>>>(R2h, R2l, aw_g, aw_be);
    proto_kernel<<<C / SS, blk, 0, stream>>>(R2h, R2l, lab + sc * C,
                                             protos + (size_t)sc * (C / SS) * H);
  }
  pn_kernel<<<NS, blk, 0, stream>>>(protos, pn);

  // ---- query chunks ----
  for (int qc = 0; qc < T_Q / C; qc++) {
    const float* q0 = qry + (size_t)qc * C * H;
    adapt_f<<<C, 64, 0, stream>>>(q0, protos, pn, R0h, R0l);
    gemm3<true ><<<gg, blk, 0, stream>>>(R0h, R0l, R0h, R0l, ad1h, ad1l, ad_b1, R1h, R1l, C, H, H, H);
    gemm3<false><<<gg, blk, 0, stream>>>(R1h, R1l, R1h, R1l, ad2h, ad2l, ad_b2, R2h, R2l, C, H, H, H);
    for (int it = 1; it < 5; it++) {
      adapt_b<<<C, 64, 0, stream>>>(R2h, R2l, protos, pn, R0h, R0l);
      gemm3<true ><<<gg, blk, 0, stream>>>(R0h, R0l, R0h, R0l, ad1h, ad1l, ad_b1, R1h, R1l, C, H, H, H);
      gemm3<false><<<gg, blk, 0, stream>>>(R1h, R1l, R1h, R1l, ad2h, ad2l, ad_b2, R2h, R2l, C, H, H, H);
    }
    // aspect_aware head -> R1 = q_aw
    gemm3<true ><<<gg, blk, 0, stream>>>(R2h, R2l, R2h, R2l, aw1h, aw1l, aw_b1, R0h, R0l, C, H, H, H);
    gemm3<false><<<gg, blk, 0, stream>>>(R0h, R0l, R0h, R0l, aw2h, aw2l, aw_b2, R1h, R1l, C, H, H, H);
    ln_pair<<<C, blk, 0, stream>>>(R1h, R1l, aw_g, aw_be);
    // contrastive head -> R2 = q_ct (adapted consumed)
    gemm3<true ><<<gg, blk, 0, stream>>>(R2h, R2l, R2h, R2l, ct1h, ct1l, ct_b1, R0h, R0l, C, H, H, H);
    gemm3<false><<<gg, blk, 0, stream>>>(R0h, R0l, R0h, R0l, ct2h, ct2l, ct_b2, R2h, R2l, C, H, H, H);
    ln_pair<<<C, blk, 0, stream>>>(R2h, R2l, ct_g, ct_be);
    // classifier h1 = relu([q_aw | q_ct] @ cl_W1 + b1): two-pointer A, Ktot=2048
    gemm3<true ><<<gg, blk, 0, stream>>>(R1h, R1l, R2h, R2l, clW1h, clW1l, cl_b1, R0h, R0l, C, H, H, 2 * H);
    // h2 = relu(h1 @ cl_W2 + b2)  [C x 64]
    gemm_small<<<dim3(1, C / 64), blk, 0, stream>>>(R0h, R0l, cl_W2, cl_b2, h2c, C, 64, H);
    // preds -> d_out
    FewShotABSALearner_46935402610855_kernel<<<(C * 3 + 255) / 256, blk, 0, stream>>>(
        h2c, cl_W3, cl_b3, out, qc * C, C * 3, out_size);
  }
}

// Round 6
// 4714.570 us; speedup vs baseline: 2.3930x; 1.5828x over previous
//
#include <hip/hip_runtime.h>
#include <hip/hip_bf16.h>

#define H 1024
#define NS 32
#define SS 256
#define T_Q 16384            /* query tokens  (64 x 256) */
#define M_S 8192             /* support tokens (32 x 256) */

typedef __hip_bfloat16 bf16;
typedef short short8 __attribute__((ext_vector_type(8)));
typedef float floatx4 __attribute__((ext_vector_type(4)));

__device__ __forceinline__ float ldf(const bf16& v) { return __bfloat162float(v); }

// two-term bf16 split: v ~= hi + lo  (residual ~2^-16 relative)
__device__ __forceinline__ void split2(float v, bf16& h, bf16& l) {
  h = __float2bfloat16(v);
  l = __float2bfloat16(v - __bfloat162float(h));
}

// async global->LDS, 16B per lane; LDS dest = wave-uniform base + lane*16
__device__ __forceinline__ void gl2lds16(const void* g, void* l) {
  __builtin_amdgcn_global_load_lds(
      (const __attribute__((address_space(1))) unsigned int*)g,
      (__attribute__((address_space(3))) unsigned int*)l, 16, 0, 0);
}

// ---------------- fp32 -> bf16 hi/lo split convert ----------------
__global__ __launch_bounds__(256) void conv_split(const float* __restrict__ in,
                                                  bf16* __restrict__ oh,
                                                  bf16* __restrict__ ol, int n)
{
  int i = blockIdx.x * 256 + threadIdx.x;
  if (i < n) { bf16 h, l; split2(in[i], h, l); oh[i] = h; ol[i] = l; }
}

// -------- transpose + split: Wh/Wl[n][k] = split(W[k][n]).  grid (N/32, K/32) --------
__global__ __launch_bounds__(256) void transpose_split(
    const float* __restrict__ W, bf16* __restrict__ Wh, bf16* __restrict__ Wl,
    int K, int N)
{
  __shared__ float t[32][33];
  int n0 = blockIdx.x * 32, k0 = blockIdx.y * 32;
  int tx = threadIdx.x & 31, ty = threadIdx.x >> 5;
#pragma unroll
  for (int i = 0; i < 32; i += 8)
    t[ty + i][tx] = W[(size_t)(k0 + ty + i) * N + (n0 + tx)];
  __syncthreads();
#pragma unroll
  for (int i = 0; i < 32; i += 8) {
    bf16 h, l; split2(t[tx][ty + i], h, l);
    size_t o = (size_t)(n0 + ty + i) * K + (k0 + tx);
    Wh[o] = h;
    if (Wl) Wl[o] = l;
  }
}

// ---------------- split-bf16 MFMA GEMM ----------------
// C = act( [A0|A1] @ Wt^T + bias ),  computed as Ah@Wh + Al@Wh + Ah@Wl.
// A rows have stride H. Wt: [N, Ktot] pre-transposed. C: hi/lo bf16 pair [M,N].
// 128x128 tile, 256 thr (4 waves 2x2), 16x16x32 MFMA, BK=32.
// Grid is bm-major: blockIdx.x = M-stripe (same-bm blocks stride gridDim.x
// apart == 0 mod 8 -> likely same XCD -> A-stripe L2 reuse).
template<bool RELU>
__global__ __launch_bounds__(256) void gemm3(
    const bf16* __restrict__ A0h, const bf16* __restrict__ A0l,
    const bf16* __restrict__ A1h, const bf16* __restrict__ A1l,
    const bf16* __restrict__ Wh,  const bf16* __restrict__ Wl,
    const float* __restrict__ bias,
    bf16* __restrict__ Ch, bf16* __restrict__ Cl,
    int M, int N, int K0, int Ktot)
{
  __shared__ bf16 Ash[128 * 32];
  __shared__ bf16 Asl[128 * 32];
  __shared__ bf16 Bsh[128 * 32];
  __shared__ bf16 Bsl[128 * 32];
  const int tid = threadIdx.x;
  const int w = tid >> 6, l = tid & 63;
  const int bm0 = blockIdx.x * 128, bn0 = blockIdx.y * 128;
  const int wr = (w >> 1) * 64, wc = (w & 1) * 64;
  const int m16 = l & 15, quad = l >> 4;
  const bool haveWl = (Wl != nullptr);

  floatx4 acc[4][4];
#pragma unroll
  for (int i = 0; i < 4; i++)
#pragma unroll
    for (int j = 0; j < 4; j++) { acc[i][j][0]=0.f; acc[i][j][1]=0.f; acc[i][j][2]=0.f; acc[i][j][3]=0.f; }

  const int ar = w * 16 + (l >> 2);   // staging row (0..63) within half-tile
  const int ac = (l & 3) * 8;         // staging k-offset (elements)

  for (int k0 = 0; k0 < Ktot; k0 += 32) {
    const bf16 *Abh, *Abl;
    if (k0 < K0) { Abh = A0h + k0; Abl = A0l + k0; }
    else         { Abh = A1h + (k0 - K0); Abl = A1l + (k0 - K0); }
    gl2lds16(Abh + (size_t)(bm0 + ar) * H + ac,      &Ash[w * 512]);
    gl2lds16(Abh + (size_t)(bm0 + 64 + ar) * H + ac, &Ash[2048 + w * 512]);
    gl2lds16(Abl + (size_t)(bm0 + ar) * H + ac,      &Asl[w * 512]);
    gl2lds16(Abl + (size_t)(bm0 + 64 + ar) * H + ac, &Asl[2048 + w * 512]);
    const bf16* Bbh = Wh + k0;
    gl2lds16(Bbh + (size_t)(bn0 + ar) * Ktot + ac,      &Bsh[w * 512]);
    gl2lds16(Bbh + (size_t)(bn0 + 64 + ar) * Ktot + ac, &Bsh[2048 + w * 512]);
    if (haveWl) {
      const bf16* Bbl = Wl + k0;
      gl2lds16(Bbl + (size_t)(bn0 + ar) * Ktot + ac,      &Bsl[w * 512]);
      gl2lds16(Bbl + (size_t)(bn0 + 64 + ar) * Ktot + ac, &Bsl[2048 + w * 512]);
    }
    __syncthreads();

    short8 afh[4], afl[4], bfh[4], bfl[4];
#pragma unroll
    for (int mt = 0; mt < 4; mt++) {
      afh[mt] = *(const short8*)&Ash[(wr + mt * 16 + m16) * 32 + quad * 8];
      afl[mt] = *(const short8*)&Asl[(wr + mt * 16 + m16) * 32 + quad * 8];
    }
#pragma unroll
    for (int nt = 0; nt < 4; nt++)
      bfh[nt] = *(const short8*)&Bsh[(wc + nt * 16 + m16) * 32 + quad * 8];
    if (haveWl) {
#pragma unroll
      for (int nt = 0; nt < 4; nt++)
        bfl[nt] = *(const short8*)&Bsl[(wc + nt * 16 + m16) * 32 + quad * 8];
    }
#pragma unroll
    for (int mt = 0; mt < 4; mt++)
#pragma unroll
      for (int nt = 0; nt < 4; nt++) {
        acc[mt][nt] = __builtin_amdgcn_mfma_f32_16x16x32_bf16(afh[mt], bfh[nt], acc[mt][nt], 0, 0, 0);
        acc[mt][nt] = __builtin_amdgcn_mfma_f32_16x16x32_bf16(afl[mt], bfh[nt], acc[mt][nt], 0, 0, 0);
      }
    if (haveWl) {
#pragma unroll
      for (int mt = 0; mt < 4; mt++)
#pragma unroll
        for (int nt = 0; nt < 4; nt++)
          acc[mt][nt] = __builtin_amdgcn_mfma_f32_16x16x32_bf16(afh[mt], bfl[nt], acc[mt][nt], 0, 0, 0);
    }
    __syncthreads();
  }

  // epilogue: C/D layout col=lane&15, row=quad*4+reg
#pragma unroll
  for (int mt = 0; mt < 4; mt++) {
#pragma unroll
    for (int nt = 0; nt < 4; nt++) {
      int row0 = bm0 + wr + mt * 16 + quad * 4;
      int col  = bn0 + wc + nt * 16 + m16;
      float bv = bias ? bias[col] : 0.f;
#pragma unroll
      for (int r = 0; r < 4; r++) {
        float v = acc[mt][nt][r] + bv;
        if (RELU) v = fmaxf(v, 0.f);
        bf16 h, lo; split2(v, h, lo);
        size_t o = (size_t)(row0 + r) * N + col;
        Ch[o] = h; Cl[o] = lo;
      }
    }
  }
}

// ---------------- LayerNorm on hi/lo pair (fp32 stats), in place ----------------
__global__ __launch_bounds__(256) void ln_pair(
    bf16* __restrict__ hh, bf16* __restrict__ hl,
    const float* __restrict__ g, const float* __restrict__ be)
{
  int row = blockIdx.x;
  bf16* ph = hh + (size_t)row * H;
  bf16* pl = hl + (size_t)row * H;
  int tid = threadIdx.x;
  float v[4];
  float s = 0.f, sq = 0.f;
#pragma unroll
  for (int j = 0; j < 4; j++) {
    int hi = tid + 256 * j;
    v[j] = ldf(ph[hi]) + ldf(pl[hi]);
    s += v[j]; sq += v[j] * v[j];
  }
  __shared__ float rs[256], rq[256];
  rs[tid] = s; rq[tid] = sq; __syncthreads();
  for (int o = 128; o; o >>= 1) {
    if (tid < o) { rs[tid] += rs[tid + o]; rq[tid] += rq[tid + o]; }
    __syncthreads();
  }
  float mu   = rs[0] * (1.0f / H);
  float var  = rq[0] * (1.0f / H) - mu * mu;
  float rstd = rsqrtf(var + 1e-5f);
#pragma unroll
  for (int j = 0; j < 4; j++) {
    int hi = tid + 256 * j;
    bf16 h, l; split2(g[hi] * (v[j] - mu) * rstd + be[hi], h, l);
    ph[hi] = h; pl[hi] = l;
  }
}

// ------------- per-sentence masked-mean prototypes (pair in, fp32 out) -------------
__global__ __launch_bounds__(256) void proto_kernel(
    const bf16* __restrict__ eh, const bf16* __restrict__ el,
    const int* __restrict__ labels, float* __restrict__ protos_out)
{
  int p = blockIdx.x;
  int tid = threadIdx.x;
  __shared__ unsigned char lbl[SS];
  lbl[tid] = (labels[p * SS + tid] > 0) ? 1 : 0;
  __syncthreads();
  float acc[4] = {0.f, 0.f, 0.f, 0.f};
  int cnt = 0;
  const bf16* bh = eh + (size_t)p * SS * H;
  const bf16* bl = el + (size_t)p * SS * H;
  for (int s = 0; s < SS; s++) {
    if (lbl[s]) {
      cnt++;
      const bf16* rh = bh + (size_t)s * H;
      const bf16* rl = bl + (size_t)s * H;
#pragma unroll
      for (int j = 0; j < 4; j++)
        acc[j] += ldf(rh[tid + 256 * j]) + ldf(rl[tid + 256 * j]);
    }
  }
  float ic = 1.0f / fmaxf((float)cnt, 1.0f);
#pragma unroll
  for (int j = 0; j < 4; j++) protos_out[p * H + tid + 256 * j] = acc[j] * ic;
}

// ---------------- normalize prototypes -> pn (fp32) ----------------
__global__ __launch_bounds__(256) void pn_kernel(
    const float* __restrict__ protos, float* __restrict__ pn)
{
  int p = blockIdx.x;
  int tid = threadIdx.x;
  __shared__ float red[256];
  float v[4];
  float sq = 0.f;
#pragma unroll
  for (int j = 0; j < 4; j++) { v[j] = protos[p * H + tid + 256 * j]; sq += v[j] * v[j]; }
  red[tid] = sq; __syncthreads();
  for (int o = 128; o; o >>= 1) {
    if (tid < o) red[tid] += red[tid + o];
    __syncthreads();
  }
  float inv = 1.0f / fmaxf(sqrtf(red[0]), 1e-8f);
#pragma unroll
  for (int j = 0; j < 4; j++) pn[p * H + tid + 256 * j] = v[j] * inv;
}

// ---- fused cosine-sims + softmax + influence; 4 waves/block, 1 token/wave ----
__device__ __forceinline__ float wred(float v) {
#pragma unroll
  for (int o = 32; o; o >>= 1) v += __shfl_xor(v, o, 64);
  return v;
}

__device__ __forceinline__ void adapt_body(
    const float a_in[16], const float* __restrict__ protos,
    const float* __restrict__ pn, bf16* __restrict__ xh, bf16* __restrict__ xl,
    int t, int lane)
{
  float a[16];
  float ss = 0.f;
#pragma unroll
  for (int j = 0; j < 16; j++) { a[j] = a_in[j]; ss += a[j] * a[j]; }
  ss = wred(ss);
  float inv = 1.0f / fmaxf(sqrtf(ss), 1e-8f);
  float sims[NS];
#pragma unroll
  for (int p = 0; p < NS; p++) {
    const float* pr = pn + p * H;
    float part = 0.f;
#pragma unroll
    for (int j = 0; j < 16; j++) part += a[j] * pr[j * 64 + lane];
    sims[p] = wred(part) * inv;
  }
  float mx = -1e30f;
#pragma unroll
  for (int p = 0; p < NS; p++) mx = fmaxf(mx, sims[p]);
  float sum = 0.f;
#pragma unroll
  for (int p = 0; p < NS; p++) { float e = __expf(sims[p] - mx); sims[p] = e; sum += e; }
  float is = 1.0f / sum;
  bf16* xrh = xh + (size_t)t * H;
  bf16* xrl = xl + (size_t)t * H;
#pragma unroll
  for (int j = 0; j < 16; j++) {
    float v = a[j];
#pragma unroll
    for (int p = 0; p < NS; p++) v += sims[p] * is * protos[p * H + j * 64 + lane];
    bf16 h, l; split2(v, h, l);
    xrh[j * 64 + lane] = h; xrl[j * 64 + lane] = l;
  }
}

__global__ __launch_bounds__(256) void adapt_f(
    const float* __restrict__ src, const float* __restrict__ protos,
    const float* __restrict__ pn, bf16* __restrict__ xh, bf16* __restrict__ xl)
{
  int t = blockIdx.x * 4 + (threadIdx.x >> 6);
  int lane = threadIdx.x & 63;
  const float* ar = src + (size_t)t * H;
  float a[16];
#pragma unroll
  for (int j = 0; j < 16; j++) a[j] = ar[j * 64 + lane];
  adapt_body(a, protos, pn, xh, xl, t, lane);
}

__global__ __launch_bounds__(256) void adapt_b(
    const bf16* __restrict__ sh, const bf16* __restrict__ sl,
    const float* __restrict__ protos, const float* __restrict__ pn,
    bf16* __restrict__ xh, bf16* __restrict__ xl)
{
  int t = blockIdx.x * 4 + (threadIdx.x >> 6);
  int lane = threadIdx.x & 63;
  const bf16* arh = sh + (size_t)t * H;
  const bf16* arl = sl + (size_t)t * H;
  float a[16];
#pragma unroll
  for (int j = 0; j < 16; j++) a[j] = ldf(arh[j * 64 + lane]) + ldf(arl[j * 64 + lane]);
  adapt_body(a, protos, pn, xh, xl, t, lane);
}

// -------- small-N GEMM (N=64): h2 = relu(A@W + b); A = bf16 pair, W fp32, out fp32 --------
__global__ __launch_bounds__(256) void gemm_small(
    const bf16* __restrict__ Ah, const bf16* __restrict__ Al,
    const float* __restrict__ W, const float* __restrict__ bias,
    float* __restrict__ C, int M, int N, int K)
{
  const int BK = 16;
  __shared__ float As[BK][64];
  __shared__ float Bs[BK][64];
  int tid = threadIdx.x;
  int tx = tid & 15, ty = tid >> 4;
  int bn0 = blockIdx.x * 64;
  int bm0 = blockIdx.y * 64;
  float acc[4][4] = {};
  int am = tid >> 2, ak = (tid & 3) * 4;
  int bk = tid >> 4, bn = (tid & 15) * 4;
  const bf16* Aph = Ah + (size_t)(bm0 + am) * K + ak;
  const bf16* Apl = Al + (size_t)(bm0 + am) * K + ak;
  const float* Wptr = W + (size_t)bk * N + bn0 + bn;
  for (int k0 = 0; k0 < K; k0 += BK) {
#pragma unroll
    for (int c = 0; c < 4; c++) As[ak + c][am] = ldf(Aph[c]) + ldf(Apl[c]);
#pragma unroll
    for (int c = 0; c < 4; c++) Bs[bk][bn + c] = Wptr[c];
    __syncthreads();
#pragma unroll
    for (int k = 0; k < BK; k++) {
      float a[4], b[4];
#pragma unroll
      for (int i = 0; i < 4; i++) a[i] = As[k][ty * 4 + i];
#pragma unroll
      for (int j = 0; j < 4; j++) b[j] = Bs[k][tx * 4 + j];
#pragma unroll
      for (int i = 0; i < 4; i++)
#pragma unroll
        for (int j = 0; j < 4; j++)
          acc[i][j] += a[i] * b[j];
    }
    __syncthreads();
    Aph += BK; Apl += BK;
    Wptr += (size_t)BK * N;
  }
#pragma unroll
  for (int i = 0; i < 4; i++) {
    float* Crow = C + (size_t)(bm0 + ty * 4 + i) * N + bn0;
#pragma unroll
    for (int j = 0; j < 4; j++) {
      int n = tx * 4 + j;
      Crow[n] = fmaxf(acc[i][j] + bias[bn0 + n], 0.f);
    }
  }
}

// ---------------- preds chunk: out[t0+t, c] = h2[t]@W3[:,c] + b3[c] (fp32) ----------------
__global__ __launch_bounds__(256) void FewShotABSALearner_46935402610855_kernel(
    const float* __restrict__ h2, const float* __restrict__ W3,
    const float* __restrict__ b3, float* __restrict__ out,
    int t0, int nElem, int out_size)
{
  int idx = blockIdx.x * 256 + threadIdx.x;
  if (idx >= nElem) return;
  int t = idx / 3, c = idx - t * 3;
  float acc = b3[c];
  const float* hr = h2 + (size_t)t * 64;
#pragma unroll
  for (int k = 0; k < 64; k++) acc += hr[k] * W3[k * 3 + c];
  int oi = t0 * 3 + idx;
  if (oi < out_size) out[oi] = acc;
}

extern "C" void kernel_launch(void* const* d_in, const int* in_sizes, int n_in,
                              void* d_out, int out_size, void* d_ws, size_t ws_size,
                              hipStream_t stream)
{
  (void)in_sizes; (void)n_in;
  const float* sup   = (const float*)d_in[0];
  const float* qry   = (const float*)d_in[1];
  const int*   lab   = (const int*)d_in[2];
  const float *aw_W1 = (const float*)d_in[3],  *aw_b1 = (const float*)d_in[4];
  const float *aw_W2 = (const float*)d_in[5],  *aw_b2 = (const float*)d_in[6];
  const float *aw_g  = (const float*)d_in[7],  *aw_be = (const float*)d_in[8];
  const float *ct_W1 = (const float*)d_in[9],  *ct_b1 = (const float*)d_in[10];
  const float *ct_W2 = (const float*)d_in[11], *ct_b2 = (const float*)d_in[12];
  const float *ct_g  = (const float*)d_in[13], *ct_be = (const float*)d_in[14];
  const float *ad_W1 = (const float*)d_in[15], *ad_b1 = (const float*)d_in[16];
  const float *ad_W2 = (const float*)d_in[17], *ad_b2 = (const float*)d_in[18];
  const float *cl_W1 = (const float*)d_in[19], *cl_b1 = (const float*)d_in[20];
  const float *cl_W2 = (const float*)d_in[21], *cl_b2 = (const float*)d_in[22];
  const float *cl_W3 = (const float*)d_in[23], *cl_b3 = (const float*)d_in[24];
  float* out = (float*)d_out;

  // ---- adaptive chunk size from ws_size (exact byte budgets) ----
  // fixed = 12x2MB sq-wts + clW1h 4MB [+ clW1l 4MB] + protos/pn 256KB
  // per-C = 6 act bufs (C*1024*2 B) + h2c (C*256 B)
  const size_t MB = 1 << 20;
  int C; bool clLo = true;
  if      (ws_size >= (size_t)239337472) C = 16384;   // whole query set in one sweep
  else if (ws_size >= (size_t)136577024) C = 8192;
  else if (ws_size >= (size_t)85196800)  C = 4096;    // proven tier (round 5)
  else if (ws_size >= (size_t)59506688)  C = 2048;
  else if (ws_size >= (size_t)46661632)  C = 1024;
  else { C = 1024; clLo = false; }
  const int Cs = (C < M_S) ? C : M_S;                 // support chunk
  const size_t actB = (size_t)C * H * sizeof(bf16);

  char* ws = (char*)d_ws;
  size_t off = 0;
  auto nxt = [&](size_t b) { char* p = ws + off; off += b; return p; };
  bf16* sqw[12];
  for (int i = 0; i < 12; i++) sqw[i] = (bf16*)nxt(2 * MB);
  bf16 *aw1h = sqw[0], *aw1l = sqw[1], *aw2h = sqw[2],  *aw2l = sqw[3];
  bf16 *ct1h = sqw[4], *ct1l = sqw[5], *ct2h = sqw[6],  *ct2l = sqw[7];
  bf16 *ad1h = sqw[8], *ad1l = sqw[9], *ad2h = sqw[10], *ad2l = sqw[11];
  bf16* clW1h = (bf16*)nxt(4 * MB);
  bf16* clW1l = clLo ? (bf16*)nxt(4 * MB) : nullptr;
  float* protos = (float*)nxt(NS * H * 4);
  float* pn     = (float*)nxt(NS * H * 4);
  float* h2c    = (float*)nxt((size_t)C * 64 * 4);
  bf16 *R0h = (bf16*)nxt(actB), *R0l = (bf16*)nxt(actB);
  bf16 *R1h = (bf16*)nxt(actB), *R1l = (bf16*)nxt(actB);
  bf16 *R2h = (bf16*)nxt(actB), *R2l = (bf16*)nxt(actB);

  dim3 blk(256);
  dim3 tg(32, 32);
  dim3 gg(C / 128, H / 128);      // bm-major grid (swizzle for A-stripe L2 reuse)
  dim3 gs(Cs / 128, H / 128);

  // ---- weight prep: transpose + hi/lo split ----
  transpose_split<<<tg, blk, 0, stream>>>(aw_W1, aw1h, aw1l, H, H);
  transpose_split<<<tg, blk, 0, stream>>>(aw_W2, aw2h, aw2l, H, H);
  transpose_split<<<tg, blk, 0, stream>>>(ct_W1, ct1h, ct1l, H, H);
  transpose_split<<<tg, blk, 0, stream>>>(ct_W2, ct2h, ct2l, H, H);
  transpose_split<<<tg, blk, 0, stream>>>(ad_W1, ad1h, ad1l, H, H);
  transpose_split<<<tg, blk, 0, stream>>>(ad_W2, ad2h, ad2l, H, H);
  transpose_split<<<dim3(32, 64), blk, 0, stream>>>(cl_W1, clW1h, clW1l, 2 * H, H);

  // ---- support chunks -> prototypes ----
  for (int sc = 0; sc < M_S / Cs; sc++) {
    conv_split<<<(Cs * H) / 256, blk, 0, stream>>>(sup + (size_t)sc * Cs * H, R0h, R0l, Cs * H);
    gemm3<true ><<<gs, blk, 0, stream>>>(R0h, R0l, R0h, R0l, aw1h, aw1l, aw_b1, R1h, R1l, Cs, H, H, H);
    gemm3<false><<<gs, blk, 0, stream>>>(R1h, R1l, R1h, R1l, aw2h, aw2l, aw_b2, R2h, R2l, Cs, H, H, H);
    ln_pair<<<Cs, blk, 0, stream>>>(R2h, R2l, aw_g, aw_be);
    proto_kernel<<<Cs / SS, blk, 0, stream>>>(R2h, R2l, lab + sc * Cs,
                                              protos + (size_t)sc * (Cs / SS) * H);
  }
  pn_kernel<<<NS, blk, 0, stream>>>(protos, pn);

  // ---- query chunks ----
  for (int qc = 0; qc < T_Q / C; qc++) {
    const float* q0 = qry + (size_t)qc * C * H;
    adapt_f<<<C / 4, blk, 0, stream>>>(q0, protos, pn, R0h, R0l);
    gemm3<true ><<<gg, blk, 0, stream>>>(R0h, R0l, R0h, R0l, ad1h, ad1l, ad_b1, R1h, R1l, C, H, H, H);
    gemm3<false><<<gg, blk, 0, stream>>>(R1h, R1l, R1h, R1l, ad2h, ad2l, ad_b2, R2h, R2l, C, H, H, H);
    for (int it = 1; it < 5; it++) {
      adapt_b<<<C / 4, blk, 0, stream>>>(R2h, R2l, protos, pn, R0h, R0l);
      gemm3<true ><<<gg, blk, 0, stream>>>(R0h, R0l, R0h, R0l, ad1h, ad1l, ad_b1, R1h, R1l, C, H, H, H);
      gemm3<false><<<gg, blk, 0, stream>>>(R1h, R1l, R1h, R1l, ad2h, ad2l, ad_b2, R2h, R2l, C, H, H, H);
    }
    // aspect_aware head -> R1 = q_aw
    gemm3<true ><<<gg, blk, 0, stream>>>(R2h, R2l, R2h, R2l, aw1h, aw1l, aw_b1, R0h, R0l, C, H, H, H);
    gemm3<false><<<gg, blk, 0, stream>>>(R0h, R0l, R0h, R0l, aw2h, aw2l, aw_b2, R1h, R1l, C, H, H, H);
    ln_pair<<<C, blk, 0, stream>>>(R1h, R1l, aw_g, aw_be);
    // contrastive head -> R2 = q_ct (adapted consumed)
    gemm3<true ><<<gg, blk, 0, stream>>>(R2h, R2l, R2h, R2l, ct1h, ct1l, ct_b1, R0h, R0l, C, H, H, H);
    gemm3<false><<<gg, blk, 0, stream>>>(R0h, R0l, R0h, R0l, ct2h, ct2l, ct_b2, R2h, R2l, C, H, H, H);
    ln_pair<<<C, blk, 0, stream>>>(R2h, R2l, ct_g, ct_be);
    // classifier h1 = relu([q_aw | q_ct] @ cl_W1 + b1): two-pointer A, Ktot=2048
    gemm3<true ><<<gg, blk, 0, stream>>>(R1h, R1l, R2h, R2l, clW1h, clW1l, cl_b1, R0h, R0l, C, H, H, 2 * H);
    // h2 = relu(h1 @ cl_W2 + b2)  [C x 64]
    gemm_small<<<dim3(1, C / 64), blk, 0, stream>>>(R0h, R0l, cl_W2, cl_b2, h2c, C, 64, H);
    // preds -> d_out
    FewShotABSALearner_46935402610855_kernel<<<(C * 3 + 255) / 256, blk, 0, stream>>>(
        h2c, cl_W3, cl_b3, out, qc * C, C * 3, out_size);
  }
}

// Round 7
// 2796.798 us; speedup vs baseline: 4.0338x; 1.6857x over previous
//
#include <hip/hip_runtime.h>
#include <hip/hip_bf16.h>

#define H 1024
#define NS 32
#define SS 256
#define T_Q 16384            /* query tokens  (64 x 256) */
#define M_S 8192             /* support tokens (32 x 256) */

typedef __hip_bfloat16 bf16;
typedef short short8 __attribute__((ext_vector_type(8)));
typedef float floatx4 __attribute__((ext_vector_type(4)));

__device__ __forceinline__ float ldf(const bf16& v) { return __bfloat162float(v); }

// two-term bf16 split: v ~= hi + lo  (residual ~2^-16 relative)
__device__ __forceinline__ void split2(float v, bf16& h, bf16& l) {
  h = __float2bfloat16(v);
  l = __float2bfloat16(v - __bfloat162float(h));
}

// async global->LDS, 16B per lane; LDS dest = wave-uniform base + lane*16
__device__ __forceinline__ void gl2lds16(const void* g, void* l) {
  __builtin_amdgcn_global_load_lds(
      (const __attribute__((address_space(1))) unsigned int*)g,
      (__attribute__((address_space(3))) unsigned int*)l, 16, 0, 0);
}

// ---------------- fp32 -> bf16 hi/lo split convert ----------------
__global__ __launch_bounds__(256) void conv_split(const float* __restrict__ in,
                                                  bf16* __restrict__ oh,
                                                  bf16* __restrict__ ol, int n)
{
  int i = blockIdx.x * 256 + threadIdx.x;
  if (i < n) { bf16 h, l; split2(in[i], h, l); oh[i] = h; ol[i] = l; }
}

// -------- transpose + split: Wh/Wl[n][k] = split(W[k][n]).  grid (N/32, K/32) --------
__global__ __launch_bounds__(256) void transpose_split(
    const float* __restrict__ W, bf16* __restrict__ Wh, bf16* __restrict__ Wl,
    int K, int N)
{
  __shared__ float t[32][33];
  int n0 = blockIdx.x * 32, k0 = blockIdx.y * 32;
  int tx = threadIdx.x & 31, ty = threadIdx.x >> 5;
#pragma unroll
  for (int i = 0; i < 32; i += 8)
    t[ty + i][tx] = W[(size_t)(k0 + ty + i) * N + (n0 + tx)];
  __syncthreads();
#pragma unroll
  for (int i = 0; i < 32; i += 8) {
    bf16 h, l; split2(t[tx][ty + i], h, l);
    size_t o = (size_t)(n0 + ty + i) * K + (k0 + tx);
    Wh[o] = h;
    if (Wl) Wl[o] = l;
  }
}

// ---------------- split-bf16 MFMA GEMM ----------------
// C = act( [A0|A1] @ Wt^T + bias ),  computed as Ah@Wh + Al@Wh + Ah@Wl.
// 128x128 tile, 256 thr (4 waves 2x2), 16x16x32 MFMA, BK=32. bm-major grid.
template<bool RELU>
__global__ __launch_bounds__(256) void gemm3(
    const bf16* __restrict__ A0h, const bf16* __restrict__ A0l,
    const bf16* __restrict__ A1h, const bf16* __restrict__ A1l,
    const bf16* __restrict__ Wh,  const bf16* __restrict__ Wl,
    const float* __restrict__ bias,
    bf16* __restrict__ Ch, bf16* __restrict__ Cl,
    int M, int N, int K0, int Ktot)
{
  __shared__ bf16 Ash[128 * 32];
  __shared__ bf16 Asl[128 * 32];
  __shared__ bf16 Bsh[128 * 32];
  __shared__ bf16 Bsl[128 * 32];
  const int tid = threadIdx.x;
  const int w = tid >> 6, l = tid & 63;
  const int bm0 = blockIdx.x * 128, bn0 = blockIdx.y * 128;
  const int wr = (w >> 1) * 64, wc = (w & 1) * 64;
  const int m16 = l & 15, quad = l >> 4;
  const bool haveWl = (Wl != nullptr);

  floatx4 acc[4][4];
#pragma unroll
  for (int i = 0; i < 4; i++)
#pragma unroll
    for (int j = 0; j < 4; j++) { acc[i][j][0]=0.f; acc[i][j][1]=0.f; acc[i][j][2]=0.f; acc[i][j][3]=0.f; }

  const int ar = w * 16 + (l >> 2);   // staging row within half-tile
  const int ac = (l & 3) * 8;         // staging k-offset (elements)

  for (int k0 = 0; k0 < Ktot; k0 += 32) {
    const bf16 *Abh, *Abl;
    if (k0 < K0) { Abh = A0h + k0; Abl = A0l + k0; }
    else         { Abh = A1h + (k0 - K0); Abl = A1l + (k0 - K0); }
    gl2lds16(Abh + (size_t)(bm0 + ar) * H + ac,      &Ash[w * 512]);
    gl2lds16(Abh + (size_t)(bm0 + 64 + ar) * H + ac, &Ash[2048 + w * 512]);
    gl2lds16(Abl + (size_t)(bm0 + ar) * H + ac,      &Asl[w * 512]);
    gl2lds16(Abl + (size_t)(bm0 + 64 + ar) * H + ac, &Asl[2048 + w * 512]);
    const bf16* Bbh = Wh + k0;
    gl2lds16(Bbh + (size_t)(bn0 + ar) * Ktot + ac,      &Bsh[w * 512]);
    gl2lds16(Bbh + (size_t)(bn0 + 64 + ar) * Ktot + ac, &Bsh[2048 + w * 512]);
    if (haveWl) {
      const bf16* Bbl = Wl + k0;
      gl2lds16(Bbl + (size_t)(bn0 + ar) * Ktot + ac,      &Bsl[w * 512]);
      gl2lds16(Bbl + (size_t)(bn0 + 64 + ar) * Ktot + ac, &Bsl[2048 + w * 512]);
    }
    __syncthreads();

    short8 afh[4], afl[4], bfh[4], bfl[4];
#pragma unroll
    for (int mt = 0; mt < 4; mt++) {
      afh[mt] = *(const short8*)&Ash[(wr + mt * 16 + m16) * 32 + quad * 8];
      afl[mt] = *(const short8*)&Asl[(wr + mt * 16 + m16) * 32 + quad * 8];
    }
#pragma unroll
    for (int nt = 0; nt < 4; nt++)
      bfh[nt] = *(const short8*)&Bsh[(wc + nt * 16 + m16) * 32 + quad * 8];
    if (haveWl) {
#pragma unroll
      for (int nt = 0; nt < 4; nt++)
        bfl[nt] = *(const short8*)&Bsl[(wc + nt * 16 + m16) * 32 + quad * 8];
    }
#pragma unroll
    for (int mt = 0; mt < 4; mt++)
#pragma unroll
      for (int nt = 0; nt < 4; nt++) {
        acc[mt][nt] = __builtin_amdgcn_mfma_f32_16x16x32_bf16(afh[mt], bfh[nt], acc[mt][nt], 0, 0, 0);
        acc[mt][nt] = __builtin_amdgcn_mfma_f32_16x16x32_bf16(afl[mt], bfh[nt], acc[mt][nt], 0, 0, 0);
      }
    if (haveWl) {
#pragma unroll
      for (int mt = 0; mt < 4; mt++)
#pragma unroll
        for (int nt = 0; nt < 4; nt++)
          acc[mt][nt] = __builtin_amdgcn_mfma_f32_16x16x32_bf16(afh[mt], bfl[nt], acc[mt][nt], 0, 0, 0);
    }
    __syncthreads();
  }

  // epilogue: C/D layout col=lane&15, row=quad*4+reg
#pragma unroll
  for (int mt = 0; mt < 4; mt++) {
#pragma unroll
    for (int nt = 0; nt < 4; nt++) {
      int row0 = bm0 + wr + mt * 16 + quad * 4;
      int col  = bn0 + wc + nt * 16 + m16;
      float bv = bias ? bias[col] : 0.f;
#pragma unroll
      for (int r = 0; r < 4; r++) {
        float v = acc[mt][nt][r] + bv;
        if (RELU) v = fmaxf(v, 0.f);
        bf16 h, lo; split2(v, h, lo);
        size_t o = (size_t)(row0 + r) * N + col;
        Ch[o] = h; Cl[o] = lo;
      }
    }
  }
}

// ---------------- LayerNorm on hi/lo pair (fp32 stats), in place ----------------
__global__ __launch_bounds__(256) void ln_pair(
    bf16* __restrict__ hh, bf16* __restrict__ hl,
    const float* __restrict__ g, const float* __restrict__ be)
{
  int row = blockIdx.x;
  bf16* ph = hh + (size_t)row * H;
  bf16* pl = hl + (size_t)row * H;
  int tid = threadIdx.x;
  float v[4];
  float s = 0.f, sq = 0.f;
#pragma unroll
  for (int j = 0; j < 4; j++) {
    int hi = tid + 256 * j;
    v[j] = ldf(ph[hi]) + ldf(pl[hi]);
    s += v[j]; sq += v[j] * v[j];
  }
  __shared__ float rs[256], rq[256];
  rs[tid] = s; rq[tid] = sq; __syncthreads();
  for (int o = 128; o; o >>= 1) {
    if (tid < o) { rs[tid] += rs[tid + o]; rq[tid] += rq[tid + o]; }
    __syncthreads();
  }
  float mu   = rs[0] * (1.0f / H);
  float var  = rq[0] * (1.0f / H) - mu * mu;
  float rstd = rsqrtf(var + 1e-5f);
#pragma unroll
  for (int j = 0; j < 4; j++) {
    int hi = tid + 256 * j;
    bf16 h, l; split2(g[hi] * (v[j] - mu) * rstd + be[hi], h, l);
    ph[hi] = h; pl[hi] = l;
  }
}

// ------------- per-sentence masked-mean prototypes (pair in, fp32 out) -------------
__global__ __launch_bounds__(256) void proto_kernel(
    const bf16* __restrict__ eh, const bf16* __restrict__ el,
    const int* __restrict__ labels, float* __restrict__ protos_out)
{
  int p = blockIdx.x;
  int tid = threadIdx.x;
  __shared__ unsigned char lbl[SS];
  lbl[tid] = (labels[p * SS + tid] > 0) ? 1 : 0;
  __syncthreads();
  float acc[4] = {0.f, 0.f, 0.f, 0.f};
  int cnt = 0;
  const bf16* bh = eh + (size_t)p * SS * H;
  const bf16* bl = el + (size_t)p * SS * H;
  for (int s = 0; s < SS; s++) {
    if (lbl[s]) {
      cnt++;
      const bf16* rh = bh + (size_t)s * H;
      const bf16* rl = bl + (size_t)s * H;
#pragma unroll
      for (int j = 0; j < 4; j++)
        acc[j] += ldf(rh[tid + 256 * j]) + ldf(rl[tid + 256 * j]);
    }
  }
  float ic = 1.0f / fmaxf((float)cnt, 1.0f);
#pragma unroll
  for (int j = 0; j < 4; j++) protos_out[p * H + tid + 256 * j] = acc[j] * ic;
}

// ---------------- normalize prototypes -> pn bf16 hi/lo pair ----------------
__global__ __launch_bounds__(256) void pn_kernel(
    const float* __restrict__ protos, bf16* __restrict__ pnh, bf16* __restrict__ pnl)
{
  int p = blockIdx.x;
  int tid = threadIdx.x;
  __shared__ float red[256];
  float v[4];
  float sq = 0.f;
#pragma unroll
  for (int j = 0; j < 4; j++) { v[j] = protos[p * H + tid + 256 * j]; sq += v[j] * v[j]; }
  red[tid] = sq; __syncthreads();
  for (int o = 128; o; o >>= 1) {
    if (tid < o) red[tid] += red[tid + o];
    __syncthreads();
  }
  float inv = 1.0f / fmaxf(sqrtf(red[0]), 1e-8f);
#pragma unroll
  for (int j = 0; j < 4; j++) {
    bf16 h, l; split2(v[j] * inv, h, l);
    pnh[p * H + tid + 256 * j] = h;
    pnl[p * H + tid + 256 * j] = l;
  }
}

// ---------------- rownorm: rn[row] = 1/max(||h+l||, 1e-8) ----------------
__global__ __launch_bounds__(256) void rownorm_pair(
    const bf16* __restrict__ hh, const bf16* __restrict__ hl, float* __restrict__ rn)
{
  int row = blockIdx.x;
  int tid = threadIdx.x;
  const bf16* ph = hh + (size_t)row * H;
  const bf16* pl = hl + (size_t)row * H;
  float s = 0.f;
#pragma unroll
  for (int j = 0; j < 4; j++) {
    float v = ldf(ph[tid + 256 * j]) + ldf(pl[tid + 256 * j]);
    s += v * v;
  }
  __shared__ float rs[256];
  rs[tid] = s; __syncthreads();
  for (int o = 128; o; o >>= 1) {
    if (tid < o) rs[tid] += rs[tid + o];
    __syncthreads();
  }
  if (tid == 0) rn[row] = 1.0f / fmaxf(sqrtf(rs[0]), 1e-8f);
}

// ---------------- sims = A_pair @ pn_pair^T  (split-3 MFMA, N=32) ----------------
// M-tile 64, 4 waves (wave w owns rows w*16..w*16+15), K=1024, BK=32.
__global__ __launch_bounds__(256) void sims_mfma(
    const bf16* __restrict__ Ah, const bf16* __restrict__ Al,
    const bf16* __restrict__ Bh, const bf16* __restrict__ Bl,
    float* __restrict__ sims)
{
  __shared__ bf16 AsH[64 * 32];
  __shared__ bf16 AsL[64 * 32];
  __shared__ bf16 BsH[32 * 32];
  __shared__ bf16 BsL[32 * 32];
  const int tid = threadIdx.x;
  const int w = tid >> 6, l = tid & 63;
  const int bm0 = blockIdx.x * 64;
  const int m16 = l & 15, quad = l >> 4;
  const int sr = l >> 2;           // staging row within wave segment
  const int sc = (l & 3) * 8;      // staging k-offset

  floatx4 acc[2];
#pragma unroll
  for (int nt = 0; nt < 2; nt++) { acc[nt][0]=0.f; acc[nt][1]=0.f; acc[nt][2]=0.f; acc[nt][3]=0.f; }

  for (int k0 = 0; k0 < H; k0 += 32) {
    gl2lds16(Ah + (size_t)(bm0 + w * 16 + sr) * H + k0 + sc, &AsH[w * 512]);
    gl2lds16(Al + (size_t)(bm0 + w * 16 + sr) * H + k0 + sc, &AsL[w * 512]);
    if (w < 2) gl2lds16(Bh + (size_t)(w * 16 + sr) * H + k0 + sc, &BsH[w * 512]);
    else       gl2lds16(Bl + (size_t)((w - 2) * 16 + sr) * H + k0 + sc, &BsL[(w - 2) * 512]);
    __syncthreads();

    short8 ah  = *(const short8*)&AsH[(w * 16 + m16) * 32 + quad * 8];
    short8 al8 = *(const short8*)&AsL[(w * 16 + m16) * 32 + quad * 8];
#pragma unroll
    for (int nt = 0; nt < 2; nt++) {
      short8 bh  = *(const short8*)&BsH[(nt * 16 + m16) * 32 + quad * 8];
      short8 bl8 = *(const short8*)&BsL[(nt * 16 + m16) * 32 + quad * 8];
      acc[nt] = __builtin_amdgcn_mfma_f32_16x16x32_bf16(ah,  bh,  acc[nt], 0, 0, 0);
      acc[nt] = __builtin_amdgcn_mfma_f32_16x16x32_bf16(al8, bh,  acc[nt], 0, 0, 0);
      acc[nt] = __builtin_amdgcn_mfma_f32_16x16x32_bf16(ah,  bl8, acc[nt], 0, 0, 0);
    }
    __syncthreads();
  }

#pragma unroll
  for (int nt = 0; nt < 2; nt++) {
    int col  = nt * 16 + m16;
    int row0 = bm0 + w * 16 + quad * 4;
#pragma unroll
    for (int r = 0; r < 4; r++)
      sims[(size_t)(row0 + r) * 32 + col] = acc[nt][r];
  }
}

// ---------------- softmax over 32 protos; half-wave per token ----------------
__global__ __launch_bounds__(256) void softmax32(
    const float* __restrict__ sims, const float* __restrict__ rn,
    float* __restrict__ wts)
{
  int t = blockIdx.x * 8 + (threadIdx.x >> 5);
  int p = threadIdx.x & 31;
  float s = sims[(size_t)t * 32 + p] * rn[t];
  float m = s;
#pragma unroll
  for (int o = 16; o; o >>= 1) m = fmaxf(m, __shfl_xor(m, o, 64));
  float e = __expf(s - m);
  float sum = e;
#pragma unroll
  for (int o = 16; o; o >>= 1) sum += __shfl_xor(sum, o, 64);
  wts[(size_t)t * 32 + p] = e / sum;
}

// -------- influence: out = a + wts @ protos; 16 tokens/block, fp32-exact --------
__global__ __launch_bounds__(256) void infl16(
    const bf16* __restrict__ ah, const bf16* __restrict__ al,
    const float* __restrict__ wts, const float* __restrict__ protos,
    bf16* __restrict__ oh, bf16* __restrict__ ol)
{
  int t0 = blockIdx.x * 16;
  int tid = threadIdx.x;
  __shared__ float wl[16][32];
  for (int i = tid; i < 512; i += 256)
    wl[i >> 5][i & 31] = wts[(size_t)(t0 + (i >> 5)) * 32 + (i & 31)];
  __syncthreads();
  int c0 = tid * 4;
  float acc[16][4];
#pragma unroll
  for (int tk = 0; tk < 16; tk++) {
    const bf16* rh = ah + (size_t)(t0 + tk) * H + c0;
    const bf16* rl = al + (size_t)(t0 + tk) * H + c0;
#pragma unroll
    for (int j = 0; j < 4; j++) acc[tk][j] = ldf(rh[j]) + ldf(rl[j]);
  }
  for (int p = 0; p < 32; p++) {
    float4 pv = *(const float4*)&protos[p * H + c0];
#pragma unroll
    for (int tk = 0; tk < 16; tk++) {
      float w = wl[tk][p];
      acc[tk][0] += w * pv.x; acc[tk][1] += w * pv.y;
      acc[tk][2] += w * pv.z; acc[tk][3] += w * pv.w;
    }
  }
#pragma unroll
  for (int tk = 0; tk < 16; tk++) {
    bf16* wh = oh + (size_t)(t0 + tk) * H + c0;
    bf16* wo = ol + (size_t)(t0 + tk) * H + c0;
#pragma unroll
    for (int j = 0; j < 4; j++) { bf16 h, lo; split2(acc[tk][j], h, lo); wh[j] = h; wo[j] = lo; }
  }
}

// -------- small-N GEMM (N=64): h2 = relu(A@W + b); A = bf16 pair, W fp32, out fp32 --------
__global__ __launch_bounds__(256) void gemm_small(
    const bf16* __restrict__ Ah, const bf16* __restrict__ Al,
    const float* __restrict__ W, const float* __restrict__ bias,
    float* __restrict__ C, int M, int N, int K)
{
  const int BK = 16;
  __shared__ float As[BK][64];
  __shared__ float Bs[BK][64];
  int tid = threadIdx.x;
  int tx = tid & 15, ty = tid >> 4;
  int bn0 = blockIdx.x * 64;
  int bm0 = blockIdx.y * 64;
  float acc[4][4] = {};
  int am = tid >> 2, ak = (tid & 3) * 4;
  int bk = tid >> 4, bn = (tid & 15) * 4;
  const bf16* Aph = Ah + (size_t)(bm0 + am) * K + ak;
  const bf16* Apl = Al + (size_t)(bm0 + am) * K + ak;
  const float* Wptr = W + (size_t)bk * N + bn0 + bn;
  for (int k0 = 0; k0 < K; k0 += BK) {
#pragma unroll
    for (int c = 0; c < 4; c++) As[ak + c][am] = ldf(Aph[c]) + ldf(Apl[c]);
#pragma unroll
    for (int c = 0; c < 4; c++) Bs[bk][bn + c] = Wptr[c];
    __syncthreads();
#pragma unroll
    for (int k = 0; k < BK; k++) {
      float a[4], b[4];
#pragma unroll
      for (int i = 0; i < 4; i++) a[i] = As[k][ty * 4 + i];
#pragma unroll
      for (int j = 0; j < 4; j++) b[j] = Bs[k][tx * 4 + j];
#pragma unroll
      for (int i = 0; i < 4; i++)
#pragma unroll
        for (int j = 0; j < 4; j++)
          acc[i][j] += a[i] * b[j];
    }
    __syncthreads();
    Aph += BK; Apl += BK;
    Wptr += (size_t)BK * N;
  }
#pragma unroll
  for (int i = 0; i < 4; i++) {
    float* Crow = C + (size_t)(bm0 + ty * 4 + i) * N + bn0;
#pragma unroll
    for (int j = 0; j < 4; j++) {
      int n = tx * 4 + j;
      Crow[n] = fmaxf(acc[i][j] + bias[bn0 + n], 0.f);
    }
  }
}

// ---------------- preds chunk: out[t0+t, c] = h2[t]@W3[:,c] + b3[c] (fp32) ----------------
__global__ __launch_bounds__(256) void FewShotABSALearner_46935402610855_kernel(
    const float* __restrict__ h2, const float* __restrict__ W3,
    const float* __restrict__ b3, float* __restrict__ out,
    int t0, int nElem, int out_size)
{
  int idx = blockIdx.x * 256 + threadIdx.x;
  if (idx >= nElem) return;
  int t = idx / 3, c = idx - t * 3;
  float acc = b3[c];
  const float* hr = h2 + (size_t)t * 64;
#pragma unroll
  for (int k = 0; k < 64; k++) acc += hr[k] * W3[k * 3 + c];
  int oi = t0 * 3 + idx;
  if (oi < out_size) out[oi] = acc;
}

extern "C" void kernel_launch(void* const* d_in, const int* in_sizes, int n_in,
                              void* d_out, int out_size, void* d_ws, size_t ws_size,
                              hipStream_t stream)
{
  (void)in_sizes; (void)n_in;
  const float* sup   = (const float*)d_in[0];
  const float* qry   = (const float*)d_in[1];
  const int*   lab   = (const int*)d_in[2];
  const float *aw_W1 = (const float*)d_in[3],  *aw_b1 = (const float*)d_in[4];
  const float *aw_W2 = (const float*)d_in[5],  *aw_b2 = (const float*)d_in[6];
  const float *aw_g  = (const float*)d_in[7],  *aw_be = (const float*)d_in[8];
  const float *ct_W1 = (const float*)d_in[9],  *ct_b1 = (const float*)d_in[10];
  const float *ct_W2 = (const float*)d_in[11], *ct_b2 = (const float*)d_in[12];
  const float *ct_g  = (const float*)d_in[13], *ct_be = (const float*)d_in[14];
  const float *ad_W1 = (const float*)d_in[15], *ad_b1 = (const float*)d_in[16];
  const float *ad_W2 = (const float*)d_in[17], *ad_b2 = (const float*)d_in[18];
  const float *cl_W1 = (const float*)d_in[19], *cl_b1 = (const float*)d_in[20];
  const float *cl_W2 = (const float*)d_in[21], *cl_b2 = (const float*)d_in[22];
  const float *cl_W3 = (const float*)d_in[23], *cl_b3 = (const float*)d_in[24];
  float* out = (float*)d_out;

  // ---- adaptive chunk size from ws_size (exact byte budgets) ----
  // fixed = 12x2MB sq-wts + clW1h 4MB [+ clW1l 4MB] + protos 128KB + pn pair 128KB
  // per-C = 6 act (C*2048 B) + union h2c|sims+wts (C*256 B) + rn (C*4 B) = 12548*C
  const size_t MB = 1 << 20;
  int C; bool clLo = true;
  if      (ws_size >= (size_t)239403008) C = 16384;
  else if (ws_size >= (size_t)136609792) C = 8192;
  else if (ws_size >= (size_t)85213184)  C = 4096;
  else if (ws_size >= (size_t)59514880)  C = 2048;
  else if (ws_size >= (size_t)46665728)  C = 1024;
  else { C = 1024; clLo = false; }
  const int Cs = (C < M_S) ? C : M_S;                 // support chunk
  const size_t actB = (size_t)C * H * sizeof(bf16);

  char* ws = (char*)d_ws;
  size_t off = 0;
  auto nxt = [&](size_t b) { char* p = ws + off; off += b; return p; };
  bf16* sqw[12];
  for (int i = 0; i < 12; i++) sqw[i] = (bf16*)nxt(2 * MB);
  bf16 *aw1h = sqw[0], *aw1l = sqw[1], *aw2h = sqw[2],  *aw2l = sqw[3];
  bf16 *ct1h = sqw[4], *ct1l = sqw[5], *ct2h = sqw[6],  *ct2l = sqw[7];
  bf16 *ad1h = sqw[8], *ad1l = sqw[9], *ad2h = sqw[10], *ad2l = sqw[11];
  bf16* clW1h = (bf16*)nxt(4 * MB);
  bf16* clW1l = clLo ? (bf16*)nxt(4 * MB) : nullptr;
  float* protos = (float*)nxt(NS * H * 4);
  bf16*  pnh    = (bf16*)nxt(NS * H * 2);
  bf16*  pnl    = (bf16*)nxt(NS * H * 2);
  char*  ub     = nxt((size_t)C * 256);               // union: h2c | sims+wts
  float* h2c   = (float*)ub;
  float* simsb = (float*)ub;
  float* wtsb  = (float*)(ub + (size_t)C * 128);
  float* rn    = (float*)nxt((size_t)C * 4);
  bf16 *R0h = (bf16*)nxt(actB), *R0l = (bf16*)nxt(actB);
  bf16 *R1h = (bf16*)nxt(actB), *R1l = (bf16*)nxt(actB);
  bf16 *R2h = (bf16*)nxt(actB), *R2l = (bf16*)nxt(actB);

  dim3 blk(256);
  dim3 tg(32, 32);
  dim3 gg(C / 128, H / 128);      // bm-major grid
  dim3 gs(Cs / 128, H / 128);

  // ---- weight prep: transpose + hi/lo split ----
  transpose_split<<<tg, blk, 0, stream>>>(aw_W1, aw1h, aw1l, H, H);
  transpose_split<<<tg, blk, 0, stream>>>(aw_W2, aw2h, aw2l, H, H);
  transpose_split<<<tg, blk, 0, stream>>>(ct_W1, ct1h, ct1l, H, H);
  transpose_split<<<tg, blk, 0, stream>>>(ct_W2, ct2h, ct2l, H, H);
  transpose_split<<<tg, blk, 0, stream>>>(ad_W1, ad1h, ad1l, H, H);
  transpose_split<<<tg, blk, 0, stream>>>(ad_W2, ad2h, ad2l, H, H);
  transpose_split<<<dim3(32, 64), blk, 0, stream>>>(cl_W1, clW1h, clW1l, 2 * H, H);

  // ---- support chunks -> prototypes ----
  for (int sc = 0; sc < M_S / Cs; sc++) {
    conv_split<<<(Cs * H) / 256, blk, 0, stream>>>(sup + (size_t)sc * Cs * H, R0h, R0l, Cs * H);
    gemm3<true ><<<gs, blk, 0, stream>>>(R0h, R0l, R0h, R0l, aw1h, aw1l, aw_b1, R1h, R1l, Cs, H, H, H);
    gemm3<false><<<gs, blk, 0, stream>>>(R1h, R1l, R1h, R1l, aw2h, aw2l, aw_b2, R2h, R2l, Cs, H, H, H);
    ln_pair<<<Cs, blk, 0, stream>>>(R2h, R2l, aw_g, aw_be);
    proto_kernel<<<Cs / SS, blk, 0, stream>>>(R2h, R2l, lab + sc * Cs,
                                              protos + (size_t)sc * (Cs / SS) * H);
  }
  pn_kernel<<<NS, blk, 0, stream>>>(protos, pnh, pnl);

  // ---- query chunks ----
  for (int qc = 0; qc < T_Q / C; qc++) {
    const float* q0 = qry + (size_t)qc * C * H;
    conv_split<<<(C * H) / 256, blk, 0, stream>>>(q0, R2h, R2l, C * H);
    for (int it = 0; it < 5; it++) {
      rownorm_pair<<<C, blk, 0, stream>>>(R2h, R2l, rn);
      sims_mfma<<<C / 64, blk, 0, stream>>>(R2h, R2l, pnh, pnl, simsb);
      softmax32<<<C / 8, blk, 0, stream>>>(simsb, rn, wtsb);
      infl16<<<C / 16, blk, 0, stream>>>(R2h, R2l, wtsb, protos, R0h, R0l);
      gemm3<true ><<<gg, blk, 0, stream>>>(R0h, R0l, R0h, R0l, ad1h, ad1l, ad_b1, R1h, R1l, C, H, H, H);
      gemm3<false><<<gg, blk, 0, stream>>>(R1h, R1l, R1h, R1l, ad2h, ad2l, ad_b2, R2h, R2l, C, H, H, H);
    }
    // aspect_aware head -> R1 = q_aw
    gemm3<true ><<<gg, blk, 0, stream>>>(R2h, R2l, R2h, R2l, aw1h, aw1l, aw_b1, R0h, R0l, C, H, H, H);
    gemm3<false><<<gg, blk, 0, stream>>>(R0h, R0l, R0h, R0l, aw2h, aw2l, aw_b2, R1h, R1l, C, H, H, H);
    ln_pair<<<C, blk, 0, stream>>>(R1h, R1l, aw_g, aw_be);
    // contrastive head -> R2 = q_ct (adapted consumed)
    gemm3<true ><<<gg, blk, 0, stream>>>(R2h, R2l, R2h, R2l, ct1h, ct1l, ct_b1, R0h, R0l, C, H, H, H);
    gemm3<false><<<gg, blk, 0, stream>>>(R0h, R0l, R0h, R0l, ct2h, ct2l, ct_b2, R2h, R2l, C, H, H, H);
    ln_pair<<<C, blk, 0, stream>>>(R2h, R2l, ct_g, ct_be);
    // classifier h1 = relu([q_aw | q_ct] @ cl_W1 + b1): two-pointer A, Ktot=2048
    gemm3<true ><<<gg, blk, 0, stream>>>(R1h, R1l, R2h, R2l, clW1h, clW1l, cl_b1, R0h, R0l, C, H, H, 2 * H);
    // h2 = relu(h1 @ cl_W2 + b2)  [C x 64]
    gemm_small<<<dim3(1, C / 64), blk, 0, stream>>>(R0h, R0l, cl_W2, cl_b2, h2c, C, 64, H);
    // preds -> d_out
    FewShotABSALearner_46935402610855_kernel<<<(C * 3 + 255) / 256, blk, 0, stream>>>(
        h2c, cl_W3, cl_b3, out, qc * C, C * 3, out_size);
  }
}